// Round 4
// baseline (83.966 us; speedup 1.0000x reference)
//
#include <hip/hip_runtime.h>

#define NB 32
#define NN 64
#define ND 128
#define NH 256
#define LN_EPS 1e-5f
#define IBLK 2

// Branchless erf-based exact GELU (A&S 7.1.26, |erf err| <= 1.5e-7)
__device__ __forceinline__ float gelu_fast(float x) {
    const float z  = fabsf(x) * 0.70710678118654752440f;
    const float t  = __builtin_amdgcn_rcpf(fmaf(0.3275911f, z, 1.0f));
    float p = fmaf(1.061405429f, t, -1.453152027f);
    p = fmaf(p, t, 1.421413741f);
    p = fmaf(p, t, -0.284496736f);
    p = fmaf(p, t, 0.254829592f);
    p = p * t;
    const float e  = __expf(-z * z);
    const float er = copysignf(fmaf(-p, e, 1.0f), x);
    const float sx = 0.5f * x;
    return fmaf(sx, er, sx);
}

// ---------------- K0: WC = We2 @ Wn1_bot  [NH x NH], v = be2 @ Wn1_bot [NH] ----------------
__global__ __launch_bounds__(256) void k_prep(const float* __restrict__ We2,
                                              const float* __restrict__ be2,
                                              const float* __restrict__ Wn1,
                                              float* __restrict__ WC,
                                              float* __restrict__ v) {
    const int t = threadIdx.x;
    if (blockIdx.x == 64) {
        __shared__ float bs[ND];
        if (t < ND) bs[t] = be2[t];
        __syncthreads();
        float acc = 0.f;
        #pragma unroll 4
        for (int d = 0; d < ND; ++d) acc = fmaf(bs[d], Wn1[(ND + d) * NH + t], acc);
        v[t] = acc;
        return;
    }
    const int k0 = blockIdx.x * 4;
    __shared__ float ws[4][ND];
    #pragma unroll
    for (int i = 0; i < 2; ++i) {
        const int idx = t + i * 256;
        ws[idx >> 7][idx & 127] = We2[(k0 + (idx >> 7)) * ND + (idx & 127)];
    }
    __syncthreads();
    float acc[4] = {0.f, 0.f, 0.f, 0.f};
    #pragma unroll 4
    for (int d = 0; d < ND; ++d) {
        const float wn = Wn1[(ND + d) * NH + t];
        #pragma unroll
        for (int r = 0; r < 4; ++r) acc[r] = fmaf(ws[r][d], wn, acc[r]);
    }
    #pragma unroll
    for (int r = 0; r < 4; ++r) WC[(k0 + r) * NH + t] = acc[r];
}

// ---------------- K1: Pt = x@We1_top + be1 ; Qm = x@We1_bot ; XW = x@Wn1_top ----------------
// 8 rows/block, 512 threads (two half-warps read identical weight addresses -> merged).
__global__ __launch_bounds__(512) void k_pq(const float* __restrict__ slots,
                                            const float* __restrict__ We1,
                                            const float* __restrict__ be1,
                                            const float* __restrict__ Wn1,
                                            float* __restrict__ Pt,
                                            float* __restrict__ Qm,
                                            float* __restrict__ XW) {
    __shared__ float xs[8][ND];
    const int r0   = blockIdx.x * 8;
    const int t    = threadIdx.x;
    const int c    = t & 255;
    const int half = t >> 8;
    #pragma unroll
    for (int i = 0; i < 2; ++i) {
        const int idx = t + i * 512;
        xs[idx >> 7][idx & 127] = slots[(size_t)(r0 + (idx >> 7)) * ND + (idx & 127)];
    }
    __syncthreads();
    float pt[4], qq[4], xw[4];
    const float bb = be1[c];
    #pragma unroll
    for (int r = 0; r < 4; ++r) { pt[r] = bb; qq[r] = 0.f; xw[r] = 0.f; }
    #pragma unroll 4
    for (int d = 0; d < ND; ++d) {
        const float wt  = We1[d * NH + c];
        const float wbt = We1[(ND + d) * NH + c];
        const float wn  = Wn1[d * NH + c];
        #pragma unroll
        for (int r = 0; r < 4; ++r) {
            const float x = xs[half * 4 + r][d];
            pt[r] = fmaf(x, wt,  pt[r]);
            qq[r] = fmaf(x, wbt, qq[r]);
            xw[r] = fmaf(x, wn,  xw[r]);
        }
    }
    #pragma unroll
    for (int r = 0; r < 4; ++r) {
        const size_t row = (size_t)(r0 + half * 4 + r);
        Pt[row * NH + c] = pt[r];
        Qm[row * NH + c] = qq[r];
        XW[row * NH + c] = xw[r];
    }
}

// ---------------- K2: S[row] = sum_j w_j * gelu(LN(P_i + Q_j)) ; wsum ----------------
// IBLK=2 rows/block -> 1024 blocks (4/CU, 50% occupancy).
__global__ __launch_bounds__(256) void k_msg(
    const float* __restrict__ adj,
    const float* __restrict__ Pt,
    const float* __restrict__ Qm,
    const float* __restrict__ ge,  const float* __restrict__ bge,
    float* __restrict__ Sw, float* __restrict__ wsumw)
{
    __shared__ float  lds_pt[IBLK][NH];
    __shared__ float4 lds_wmr[IBLK][NN];       // {w, mu, rr, -}
    __shared__ float  lds_s[4][IBLK][NH];
    __shared__ float  lds_redA[4][IBLK], lds_redB[4][IBLK];

    const int blk  = blockIdx.x;
    const int b    = blk >> 5;
    const int i0   = (blk & 31) * IBLK;
    const int r0   = b * NN + i0;
    const int t    = threadIdx.x;
    const int lane = t & 63;
    const int wave = t >> 6;

    #pragma unroll
    for (int r = 0; r < IBLK; ++r)
        lds_pt[r][t] = Pt[(size_t)(r0 + r) * NH + t];
    if (t < IBLK * NN) {
        const int r = t >> 6, l = t & 63;
        float av = adj[(size_t)(r0 + r) * NN + l];
        if (l == i0 + r) av = 0.f;             // diagonal mask
        lds_wmr[r][l].x = av;
        float wsv = av;
        #pragma unroll
        for (int off = 32; off; off >>= 1) wsv += __shfl_xor(wsv, off);
        if (l == 0) wsumw[r0 + r] = wsv;
    }
    __syncthreads();

    // per-row P sums
    {
        float a[IBLK], bq[IBLK];
        #pragma unroll
        for (int r = 0; r < IBLK; ++r) { const float p = lds_pt[r][t]; a[r] = p; bq[r] = p * p; }
        #pragma unroll
        for (int off = 32; off; off >>= 1) {
            #pragma unroll
            for (int r = 0; r < IBLK; ++r) {
                a[r]  += __shfl_xor(a[r],  off);
                bq[r] += __shfl_xor(bq[r], off);
            }
        }
        if (lane == 0) {
            #pragma unroll
            for (int r = 0; r < IBLK; ++r) { lds_redA[wave][r] = a[r]; lds_redB[wave][r] = bq[r]; }
        }
    }
    // C-dot prologue: j = t>>2, part = t&3, each part covers 64 channels
    const int jp   = t >> 2;
    const int part = t & 3;
    float cd[IBLK] = {0.f, 0.f};
    float qs = 0.f, qs2 = 0.f;
    {
        const float4* qrow = (const float4*)(Qm + ((size_t)b * NN + jp) * NH) + part * 16;
        #pragma unroll 4
        for (int k = 0; k < 16; ++k) {
            const int kk = (k + part * 4) & 15;     // stagger LDS banks
            const float4 q = qrow[kk];
            qs  += (q.x + q.y) + (q.z + q.w);
            qs2  = fmaf(q.x, q.x, fmaf(q.y, q.y, fmaf(q.z, q.z, fmaf(q.w, q.w, qs2))));
            #pragma unroll
            for (int r = 0; r < IBLK; ++r) {
                const float4 p = ((const float4*)lds_pt[r])[part * 16 + kk];
                cd[r] = fmaf(p.x, q.x, fmaf(p.y, q.y, fmaf(p.z, q.z, fmaf(p.w, q.w, cd[r]))));
            }
        }
        #pragma unroll
        for (int off = 1; off < 4; off <<= 1) {
            qs += __shfl_xor(qs, off); qs2 += __shfl_xor(qs2, off);
            #pragma unroll
            for (int r = 0; r < IBLK; ++r) cd[r] += __shfl_xor(cd[r], off);
        }
    }
    __syncthreads();
    if (part == 0) {
        const float inv = 1.0f / NH;
        #pragma unroll
        for (int r = 0; r < IBLK; ++r) {
            const float SP1 = (lds_redA[0][r] + lds_redA[1][r]) + (lds_redA[2][r] + lds_redA[3][r]);
            const float SP2 = (lds_redB[0][r] + lds_redB[1][r]) + (lds_redB[2][r] + lds_redB[3][r]);
            const float mu  = (SP1 + qs) * inv;
            const float e2  = (SP2 + 2.f * cd[r] + qs2) * inv;
            lds_wmr[r][jp].y = mu;
            lds_wmr[r][jp].z = __builtin_amdgcn_rsqf(e2 - mu * mu + LN_EPS);
        }
    }
    __syncthreads();

    // edge main loop: no cross-lane, no branches
    float4 P[IBLK], A[IBLK];
    #pragma unroll
    for (int r = 0; r < IBLK; ++r) {
        P[r] = ((const float4*)lds_pt[r])[lane];
        A[r] = make_float4(0.f, 0.f, 0.f, 0.f);
    }
    const float4 G  = ((const float4*)ge)[lane];
    const float4 Bg = ((const float4*)bge)[lane];
    const float4* Qb = (const float4*)(Qm + (size_t)b * NN * NH);
    #pragma unroll 4
    for (int jj = wave; jj < NN; jj += 4) {
        const float4 q = Qb[jj * (NH / 4) + lane];
        #pragma unroll
        for (int r = 0; r < IBLK; ++r) {
            const float4 wmr = lds_wmr[r][jj];
            const float wj = wmr.x, mu = wmr.y, rr = wmr.z;
            float h, u;
            h = P[r].x + q.x; u = fmaf((h - mu) * rr, G.x, Bg.x); A[r].x = fmaf(wj, gelu_fast(u), A[r].x);
            h = P[r].y + q.y; u = fmaf((h - mu) * rr, G.y, Bg.y); A[r].y = fmaf(wj, gelu_fast(u), A[r].y);
            h = P[r].z + q.z; u = fmaf((h - mu) * rr, G.z, Bg.z); A[r].z = fmaf(wj, gelu_fast(u), A[r].z);
            h = P[r].w + q.w; u = fmaf((h - mu) * rr, G.w, Bg.w); A[r].w = fmaf(wj, gelu_fast(u), A[r].w);
        }
    }
    #pragma unroll
    for (int r = 0; r < IBLK; ++r)
        ((float4*)&lds_s[wave][r][0])[lane] = A[r];
    __syncthreads();
    #pragma unroll
    for (int r = 0; r < IBLK; ++r)
        Sw[(size_t)(r0 + r) * NH + t] =
            (lds_s[0][r][t] + lds_s[1][r][t]) + (lds_s[2][r][t] + lds_s[3][r][t]);
}

// ---------------- K3: h1 = XW + S@WC + wsum*v + bn1 ; LN ; GELU ; out = x + g@Wn2 + bn2 ----------------
// 8 rows/block, 512 threads, 256 blocks.
__global__ __launch_bounds__(512) void k_node(
    const float* __restrict__ slots,
    const float* __restrict__ Sw, const float* __restrict__ wsumw,
    const float* __restrict__ XW,
    const float* __restrict__ WC, const float* __restrict__ v,
    const float* __restrict__ bn1,
    const float* __restrict__ gn,  const float* __restrict__ bgn,
    const float* __restrict__ Wn2, const float* __restrict__ bn2,
    float* __restrict__ out)
{
    __shared__ float lds_S[8][NH];
    __shared__ float lds_g[8][NH];
    __shared__ float lds_redA[8][4], lds_redB[8][4];
    __shared__ float lds_ws[8];
    __shared__ float lds_mu[8], lds_rr[8];

    const int r0   = blockIdx.x * 8;
    const int t    = threadIdx.x;
    const int c    = t & 255;
    const int half = t >> 8;
    const int wave = t >> 6;
    const int lane = t & 63;

    #pragma unroll
    for (int rr = 0; rr < 4; ++rr) {
        const int row = half * 4 + rr;
        lds_S[row][c] = Sw[(size_t)(r0 + row) * NH + c];
    }
    if (t < 8) lds_ws[t] = wsumw[r0 + t];
    __syncthreads();

    float acc[4];
    {
        const float b1 = bn1[c], vc = v[c];
        #pragma unroll
        for (int rr = 0; rr < 4; ++rr) {
            const int row = half * 4 + rr;
            acc[rr] = fmaf(lds_ws[row], vc, b1) + XW[(size_t)(r0 + row) * NH + c];
        }
    }
    #pragma unroll 8
    for (int k = 0; k < NH; ++k) {
        const float w = WC[k * NH + c];
        #pragma unroll
        for (int rr = 0; rr < 4; ++rr) acc[rr] = fmaf(lds_S[half * 4 + rr][k], w, acc[rr]);
    }

    // LN stats: per row over 256 channels (4 waves per half)
    {
        float a[4], bq[4];
        #pragma unroll
        for (int rr = 0; rr < 4; ++rr) { a[rr] = acc[rr]; bq[rr] = acc[rr] * acc[rr]; }
        #pragma unroll
        for (int off = 32; off; off >>= 1) {
            #pragma unroll
            for (int rr = 0; rr < 4; ++rr) {
                a[rr]  += __shfl_xor(a[rr],  off);
                bq[rr] += __shfl_xor(bq[rr], off);
            }
        }
        if (lane == 0) {
            #pragma unroll
            for (int rr = 0; rr < 4; ++rr) { lds_redA[wave][rr] = a[rr]; lds_redB[wave][rr] = bq[rr]; }
        }
    }
    __syncthreads();
    if (t < 8) {
        const int h = t >> 2, rr = t & 3;
        float S1 = 0.f, S2 = 0.f;
        #pragma unroll
        for (int w_ = 0; w_ < 4; ++w_) { S1 += lds_redA[h * 4 + w_][rr]; S2 += lds_redB[h * 4 + w_][rr]; }
        const float mu  = S1 * (1.0f / NH);
        const float var = S2 * (1.0f / NH) - mu * mu;
        lds_mu[t] = mu;
        lds_rr[t] = __builtin_amdgcn_rsqf(var + LN_EPS);
    }
    __syncthreads();
    {
        const float g = gn[c], bg = bgn[c];
        #pragma unroll
        for (int rr = 0; rr < 4; ++rr) {
            const int row = half * 4 + rr;
            lds_g[row][c] = gelu_fast(fmaf((acc[rr] - lds_mu[row]) * lds_rr[row], g, bg));
        }
    }
    __syncthreads();

    // delta: 4 groups x 2 rows; each wave reads one lds_g row per fma (broadcast)
    {
        const int c2 = t & 127, grp = t >> 7;
        const int ra = grp * 2, rb = grp * 2 + 1;
        float d0 = bn2[c2], d1 = d0;
        #pragma unroll 8
        for (int k = 0; k < NH; ++k) {
            const float w = Wn2[k * ND + c2];
            d0 = fmaf(lds_g[ra][k], w, d0);
            d1 = fmaf(lds_g[rb][k], w, d1);
        }
        out[(size_t)(r0 + ra) * ND + c2] = slots[(size_t)(r0 + ra) * ND + c2] + d0;
        out[(size_t)(r0 + rb) * ND + c2] = slots[(size_t)(r0 + rb) * ND + c2] + d1;
    }
}

extern "C" void kernel_launch(void* const* d_in, const int* in_sizes, int n_in,
                              void* d_out, int out_size, void* d_ws, size_t ws_size,
                              hipStream_t stream) {
    const float* slots = (const float*)d_in[0];
    const float* adj   = (const float*)d_in[1];
    const float* We1   = (const float*)d_in[2];
    const float* be1   = (const float*)d_in[3];
    const float* ge    = (const float*)d_in[4];
    const float* bge   = (const float*)d_in[5];
    const float* We2   = (const float*)d_in[6];
    const float* be2   = (const float*)d_in[7];
    const float* Wn1   = (const float*)d_in[8];
    const float* bn1   = (const float*)d_in[9];
    const float* gn    = (const float*)d_in[10];
    const float* bgn   = (const float*)d_in[11];
    const float* Wn2   = (const float*)d_in[12];
    const float* bn2   = (const float*)d_in[13];
    float* out = (float*)d_out;

    const size_t RN = (size_t)NB * NN;     // 2048
    float* Ptw   = (float*)d_ws;           // [2048,256]
    float* Qw    = Ptw   + RN * NH;        // [2048,256]
    float* XWw   = Qw    + RN * NH;        // [2048,256]
    float* Sww   = XWw   + RN * NH;        // [2048,256]
    float* wsumw = Sww   + RN * NH;        // [2048]
    float* WCw   = wsumw + RN;             // [256,256]
    float* vw    = WCw   + (size_t)NH * NH;// [256]

    k_prep<<<65,            256, 0, stream>>>(We2, be2, Wn1, WCw, vw);
    k_pq  <<<(int)(RN / 8), 512, 0, stream>>>(slots, We1, be1, Wn1, Ptw, Qw, XWw);
    k_msg <<<(int)(RN / IBLK), 256, 0, stream>>>(adj, Ptw, Qw, ge, bge, Sww, wsumw);
    k_node<<<(int)(RN / 8), 512, 0, stream>>>(slots, Sww, wsumw, XWw, WCw, vw,
                                              bn1, gn, bgn, Wn2, bn2, out);
}

// Round 5
// 71.837 us; speedup vs baseline: 1.1688x; 1.1688x over previous
//
#include <hip/hip_runtime.h>

#define NB 32
#define NN 64
#define ND 128
#define NH 256
#define LN_EPS 1e-5f
#define RP 4
#define IBLK 2

// Branchless erf-based exact GELU (A&S 7.1.26, |erf err| <= 1.5e-7)
__device__ __forceinline__ float gelu_fast(float x) {
    const float z  = fabsf(x) * 0.70710678118654752440f;
    const float t  = __builtin_amdgcn_rcpf(fmaf(0.3275911f, z, 1.0f));
    float p = fmaf(1.061405429f, t, -1.453152027f);
    p = fmaf(p, t, 1.421413741f);
    p = fmaf(p, t, -0.284496736f);
    p = fmaf(p, t, 0.254829592f);
    p = p * t;
    const float e  = __expf(-z * z);
    const float er = copysignf(fmaf(-p, e, 1.0f), x);
    const float sx = 0.5f * x;
    return fmaf(sx, er, sx);
}

// ---------------- K0: WC = We2 @ Wn1_bot [NH x NH], v = be2 @ Wn1_bot [NH] ----------------
__global__ __launch_bounds__(256) void k_prep(const float* __restrict__ We2,
                                              const float* __restrict__ be2,
                                              const float* __restrict__ Wn1,
                                              float* __restrict__ WC,
                                              float* __restrict__ v) {
    const int t = threadIdx.x;
    if (blockIdx.x == 64) {
        __shared__ float bs[ND];
        if (t < ND) bs[t] = be2[t];
        __syncthreads();
        float acc = 0.f;
        #pragma unroll 4
        for (int d = 0; d < ND; ++d) acc = fmaf(bs[d], Wn1[(ND + d) * NH + t], acc);
        v[t] = acc;
        return;
    }
    const int k0 = blockIdx.x * 4;
    __shared__ float ws[4][ND];
    #pragma unroll
    for (int i = 0; i < 2; ++i) {
        const int idx = t + i * 256;
        ws[idx >> 7][idx & 127] = We2[(k0 + (idx >> 7)) * ND + (idx & 127)];
    }
    __syncthreads();
    float acc[4] = {0.f, 0.f, 0.f, 0.f};
    #pragma unroll 4
    for (int d = 0; d < ND; ++d) {
        const float wn = Wn1[(ND + d) * NH + t];
        #pragma unroll
        for (int r = 0; r < 4; ++r) acc[r] = fmaf(ws[r][d], wn, acc[r]);
    }
    #pragma unroll
    for (int r = 0; r < 4; ++r) WC[(k0 + r) * NH + t] = acc[r];
}

// ---------------- K1: Pt/Qm/XW streams + per-row stats {SP1,SP2,SQ1,SQ2} ----------------
__global__ __launch_bounds__(256) void k_pq(const float* __restrict__ slots,
                                            const float* __restrict__ We1,
                                            const float* __restrict__ be1,
                                            const float* __restrict__ Wn1,
                                            float* __restrict__ Pt,
                                            float* __restrict__ Qm,
                                            float* __restrict__ XW,
                                            float4* __restrict__ rowstats) {
    __shared__ float xs[RP][ND];
    __shared__ float red[4][RP][4];
    const int r0 = blockIdx.x * RP;
    const int t  = threadIdx.x;
    const int lane = t & 63, wave = t >> 6;
    #pragma unroll
    for (int i = 0; i < 2; ++i) {
        const int idx = t + i * 256;
        xs[idx >> 7][idx & 127] = slots[(size_t)(r0 + (idx >> 7)) * ND + (idx & 127)];
    }
    __syncthreads();
    float pt[RP], qq[RP], xw[RP];
    const float bb = be1[t];
    #pragma unroll
    for (int r = 0; r < RP; ++r) { pt[r] = bb; qq[r] = 0.f; xw[r] = 0.f; }
    #pragma unroll 4
    for (int d = 0; d < ND; ++d) {
        const float wt  = We1[d * NH + t];
        const float wbt = We1[(ND + d) * NH + t];
        const float wn  = Wn1[d * NH + t];
        #pragma unroll
        for (int r = 0; r < RP; ++r) {
            const float x = xs[r][d];
            pt[r] = fmaf(x, wt,  pt[r]);
            qq[r] = fmaf(x, wbt, qq[r]);
            xw[r] = fmaf(x, wn,  xw[r]);
        }
    }
    #pragma unroll
    for (int r = 0; r < RP; ++r) {
        const size_t row = (size_t)(r0 + r);
        Pt[row * NH + t] = pt[r];
        Qm[row * NH + t] = qq[r];
        XW[row * NH + t] = xw[r];
    }
    // per-row stats
    float s1[RP], s2[RP], s3[RP], s4[RP];
    #pragma unroll
    for (int r = 0; r < RP; ++r) {
        s1[r] = pt[r]; s2[r] = pt[r] * pt[r];
        s3[r] = qq[r]; s4[r] = qq[r] * qq[r];
    }
    #pragma unroll
    for (int off = 32; off; off >>= 1) {
        #pragma unroll
        for (int r = 0; r < RP; ++r) {
            s1[r] += __shfl_xor(s1[r], off);
            s2[r] += __shfl_xor(s2[r], off);
            s3[r] += __shfl_xor(s3[r], off);
            s4[r] += __shfl_xor(s4[r], off);
        }
    }
    if (lane == 0) {
        #pragma unroll
        for (int r = 0; r < RP; ++r) {
            red[wave][r][0] = s1[r]; red[wave][r][1] = s2[r];
            red[wave][r][2] = s3[r]; red[wave][r][3] = s4[r];
        }
    }
    __syncthreads();
    if (t < RP) {
        float4 st;
        st.x = (red[0][t][0] + red[1][t][0]) + (red[2][t][0] + red[3][t][0]);
        st.y = (red[0][t][1] + red[1][t][1]) + (red[2][t][1] + red[3][t][1]);
        st.z = (red[0][t][2] + red[1][t][2]) + (red[2][t][2] + red[3][t][2]);
        st.w = (red[0][t][3] + red[1][t][3]) + (red[2][t][3] + red[3][t][3]);
        rowstats[r0 + t] = st;
    }
}

// ---------------- K2: S[row] = sum_j w_j * gelu(LN(P_i + Q_j)) ; wsum ----------------
__global__ __launch_bounds__(256) void k_msg(
    const float* __restrict__ adj,
    const float* __restrict__ Pt,
    const float* __restrict__ Qm,
    const float4* __restrict__ rowstats,
    const float* __restrict__ ge,  const float* __restrict__ bge,
    float* __restrict__ Sw, float* __restrict__ wsumw)
{
    __shared__ float  lds_pt[IBLK][NH];
    __shared__ float4 lds_wmr[IBLK][NN];   // {w, rr, -mu*rr, pad}
    __shared__ float  lds_wv[IBLK][NN];
    __shared__ float  lds_s[4][IBLK][NH];

    const int blk  = blockIdx.x;
    const int b    = blk >> 5;
    const int i0   = (blk & 31) * IBLK;
    const int r0   = b * NN + i0;
    const int t    = threadIdx.x;
    const int lane = t & 63;
    const int wave = t >> 6;

    lds_pt[0][t] = Pt[(size_t)r0 * NH + t];
    lds_pt[1][t] = Pt[(size_t)(r0 + 1) * NH + t];
    __syncthreads();

    // C-dot: thread (j = t>>2, part = t&3); 64 channels each
    const int jp = t >> 2, part = t & 3;
    {
        float cd0 = 0.f, cd1 = 0.f;
        const float4* qrow = (const float4*)(Qm + ((size_t)b * NN + jp) * NH) + part * 16;
        const float4* p0   = (const float4*)lds_pt[0] + part * 16;
        const float4* p1   = (const float4*)lds_pt[1] + part * 16;
        #pragma unroll 4
        for (int k = 0; k < 16; ++k) {
            const float4 q = qrow[k];
            const float4 a = p0[k];
            const float4 c = p1[k];
            cd0 = fmaf(a.x, q.x, fmaf(a.y, q.y, fmaf(a.z, q.z, fmaf(a.w, q.w, cd0))));
            cd1 = fmaf(c.x, q.x, fmaf(c.y, q.y, fmaf(c.z, q.z, fmaf(c.w, q.w, cd1))));
        }
        cd0 += __shfl_xor(cd0, 1); cd0 += __shfl_xor(cd0, 2);
        cd1 += __shfl_xor(cd1, 1); cd1 += __shfl_xor(cd1, 2);
        if (part == 0) {
            const float inv = 1.0f / NH;
            const float4 stj  = rowstats[(size_t)b * NN + jp];
            const float4 sti0 = rowstats[r0];
            const float4 sti1 = rowstats[r0 + 1];
            float a0 = adj[(size_t)r0 * NN + jp];       if (jp == i0)     a0 = 0.f;
            float a1 = adj[(size_t)(r0 + 1) * NN + jp]; if (jp == i0 + 1) a1 = 0.f;
            {
                const float mu = (sti0.x + stj.z) * inv;
                const float e2 = fmaf(2.f, cd0, sti0.y + stj.w) * inv;
                const float rr = __builtin_amdgcn_rsqf(fmaf(-mu, mu, e2) + LN_EPS);
                lds_wmr[0][jp] = make_float4(a0, rr, -mu * rr, 0.f);
                lds_wv[0][jp]  = a0;
            }
            {
                const float mu = (sti1.x + stj.z) * inv;
                const float e2 = fmaf(2.f, cd1, sti1.y + stj.w) * inv;
                const float rr = __builtin_amdgcn_rsqf(fmaf(-mu, mu, e2) + LN_EPS);
                lds_wmr[1][jp] = make_float4(a1, rr, -mu * rr, 0.f);
                lds_wv[1][jp]  = a1;
            }
        }
    }
    __syncthreads();

    // wsum (off critical path)
    if (wave < IBLK) {
        float wv = lds_wv[wave][lane];
        #pragma unroll
        for (int off = 32; off; off >>= 1) wv += __shfl_xor(wv, off);
        if (lane == 0) wsumw[r0 + wave] = wv;
    }

    // edge main loop: no cross-lane ops, no branches
    const float4 P0 = ((const float4*)lds_pt[0])[lane];
    const float4 P1 = ((const float4*)lds_pt[1])[lane];
    const float4 G  = ((const float4*)ge)[lane];
    const float4 Bg = ((const float4*)bge)[lane];
    const float4* Qb = (const float4*)(Qm + (size_t)b * NN * NH);
    float4 A0 = make_float4(0.f, 0.f, 0.f, 0.f);
    float4 A1 = make_float4(0.f, 0.f, 0.f, 0.f);
    #pragma unroll 4
    for (int jj = wave; jj < NN; jj += 4) {
        const float4 q = Qb[jj * (NH / 4) + lane];
        {
            const float4 m = lds_wmr[0][jj];
            float h, u0, u;
            h = P0.x + q.x; u0 = fmaf(h, m.y, m.z); u = fmaf(u0, G.x, Bg.x); A0.x = fmaf(m.x, gelu_fast(u), A0.x);
            h = P0.y + q.y; u0 = fmaf(h, m.y, m.z); u = fmaf(u0, G.y, Bg.y); A0.y = fmaf(m.x, gelu_fast(u), A0.y);
            h = P0.z + q.z; u0 = fmaf(h, m.y, m.z); u = fmaf(u0, G.z, Bg.z); A0.z = fmaf(m.x, gelu_fast(u), A0.z);
            h = P0.w + q.w; u0 = fmaf(h, m.y, m.z); u = fmaf(u0, G.w, Bg.w); A0.w = fmaf(m.x, gelu_fast(u), A0.w);
        }
        {
            const float4 m = lds_wmr[1][jj];
            float h, u0, u;
            h = P1.x + q.x; u0 = fmaf(h, m.y, m.z); u = fmaf(u0, G.x, Bg.x); A1.x = fmaf(m.x, gelu_fast(u), A1.x);
            h = P1.y + q.y; u0 = fmaf(h, m.y, m.z); u = fmaf(u0, G.y, Bg.y); A1.y = fmaf(m.x, gelu_fast(u), A1.y);
            h = P1.z + q.z; u0 = fmaf(h, m.y, m.z); u = fmaf(u0, G.z, Bg.z); A1.z = fmaf(m.x, gelu_fast(u), A1.z);
            h = P1.w + q.w; u0 = fmaf(h, m.y, m.z); u = fmaf(u0, G.w, Bg.w); A1.w = fmaf(m.x, gelu_fast(u), A1.w);
        }
    }
    ((float4*)&lds_s[wave][0][0])[lane] = A0;
    ((float4*)&lds_s[wave][1][0])[lane] = A1;
    __syncthreads();
    #pragma unroll
    for (int r = 0; r < IBLK; ++r)
        Sw[(size_t)(r0 + r) * NH + t] =
            (lds_s[0][r][t] + lds_s[1][r][t]) + (lds_s[2][r][t] + lds_s[3][r][t]);
}

// ---------------- K3: h1 = XW + S@WC + wsum*v + bn1 ; LN ; GELU ; out = x + g@Wn2 + bn2 ----------------
// 512 threads, 4 rows/block, k-split across halves.
__global__ __launch_bounds__(512) void k_node(
    const float* __restrict__ slots,
    const float* __restrict__ Sw, const float* __restrict__ wsumw,
    const float* __restrict__ XW,
    const float* __restrict__ WC, const float* __restrict__ v,
    const float* __restrict__ bn1,
    const float* __restrict__ gn,  const float* __restrict__ bgn,
    const float* __restrict__ Wn2, const float* __restrict__ bn2,
    float* __restrict__ out)
{
    __shared__ float lds_S[4][NH];
    __shared__ float lds_part[4][NH];
    __shared__ float lds_g[4][NH];
    __shared__ float lds_red[4][4][2];
    __shared__ float lds_mr[4][2];

    const int r0   = blockIdx.x * 4;
    const int t    = threadIdx.x;
    const int c    = t & 255;
    const int kh   = t >> 8;
    const int lane = t & 63;
    const int wave = t >> 6;

    lds_S[kh * 2 + 0][c] = Sw[(size_t)(r0 + kh * 2 + 0) * NH + c];
    lds_S[kh * 2 + 1][c] = Sw[(size_t)(r0 + kh * 2 + 1) * NH + c];
    __syncthreads();

    // phase A: partial S@WC over this half's k range
    float acc[4] = {0.f, 0.f, 0.f, 0.f};
    {
        const float* wc = WC + (size_t)kh * 128 * NH + c;
        #pragma unroll 8
        for (int k = 0; k < 128; ++k) {
            const float w = wc[k * NH];
            const int kk = kh * 128 + k;
            acc[0] = fmaf(lds_S[0][kk], w, acc[0]);
            acc[1] = fmaf(lds_S[1][kk], w, acc[1]);
            acc[2] = fmaf(lds_S[2][kk], w, acc[2]);
            acc[3] = fmaf(lds_S[3][kk], w, acc[3]);
        }
    }
    if (kh == 1) {
        #pragma unroll
        for (int r = 0; r < 4; ++r) lds_part[r][c] = acc[r];
    }
    __syncthreads();

    float h[4];
    if (kh == 0) {
        const float b1 = bn1[c], vc = v[c];
        #pragma unroll
        for (int r = 0; r < 4; ++r)
            h[r] = acc[r] + lds_part[r][c] + fmaf(wsumw[r0 + r], vc, b1)
                 + XW[(size_t)(r0 + r) * NH + c];
        float s1[4], s2[4];
        #pragma unroll
        for (int r = 0; r < 4; ++r) { s1[r] = h[r]; s2[r] = h[r] * h[r]; }
        #pragma unroll
        for (int off = 32; off; off >>= 1) {
            #pragma unroll
            for (int r = 0; r < 4; ++r) {
                s1[r] += __shfl_xor(s1[r], off);
                s2[r] += __shfl_xor(s2[r], off);
            }
        }
        if (lane == 0) {
            #pragma unroll
            for (int r = 0; r < 4; ++r) { lds_red[wave][r][0] = s1[r]; lds_red[wave][r][1] = s2[r]; }
        }
    }
    __syncthreads();
    if (t < 4) {
        const float S1 = (lds_red[0][t][0] + lds_red[1][t][0]) + (lds_red[2][t][0] + lds_red[3][t][0]);
        const float S2 = (lds_red[0][t][1] + lds_red[1][t][1]) + (lds_red[2][t][1] + lds_red[3][t][1]);
        const float mu  = S1 * (1.0f / NH);
        const float var = fmaf(-mu, mu, S2 * (1.0f / NH));
        lds_mr[t][0] = mu;
        lds_mr[t][1] = __builtin_amdgcn_rsqf(var + LN_EPS);
    }
    __syncthreads();
    if (kh == 0) {
        const float g = gn[c], bg = bgn[c];
        #pragma unroll
        for (int r = 0; r < 4; ++r) {
            const float rr = lds_mr[r][1];
            const float u0 = fmaf(h[r], rr, -lds_mr[r][0] * rr);
            lds_g[r][c] = gelu_fast(fmaf(u0, g, bg));
        }
    }
    __syncthreads();

    // phase B: delta = g @ Wn2 + bn2 ; out = x + delta
    {
        const int rg = t >> 7, c2 = t & 127;
        float da = 0.f, db = 0.f;
        const float* w2 = Wn2 + c2;
        const float* gr = lds_g[rg];
        #pragma unroll 8
        for (int k = 0; k < NH; k += 2) {
            da = fmaf(gr[k],     w2[k * ND],       da);
            db = fmaf(gr[k + 1], w2[(k + 1) * ND], db);
        }
        const size_t o = (size_t)(r0 + rg) * ND + c2;
        out[o] = slots[o] + bn2[c2] + da + db;
    }
}

extern "C" void kernel_launch(void* const* d_in, const int* in_sizes, int n_in,
                              void* d_out, int out_size, void* d_ws, size_t ws_size,
                              hipStream_t stream) {
    const float* slots = (const float*)d_in[0];
    const float* adj   = (const float*)d_in[1];
    const float* We1   = (const float*)d_in[2];
    const float* be1   = (const float*)d_in[3];
    const float* ge    = (const float*)d_in[4];
    const float* bge   = (const float*)d_in[5];
    const float* We2   = (const float*)d_in[6];
    const float* be2   = (const float*)d_in[7];
    const float* Wn1   = (const float*)d_in[8];
    const float* bn1   = (const float*)d_in[9];
    const float* gn    = (const float*)d_in[10];
    const float* bgn   = (const float*)d_in[11];
    const float* Wn2   = (const float*)d_in[12];
    const float* bn2   = (const float*)d_in[13];
    float* out = (float*)d_out;

    const size_t RN = (size_t)NB * NN;      // 2048
    float*  Ptw   = (float*)d_ws;           // [2048,256]
    float*  Qw    = Ptw   + RN * NH;        // [2048,256]
    float*  XWw   = Qw    + RN * NH;        // [2048,256]
    float*  Sww   = XWw   + RN * NH;        // [2048,256]
    float*  wsumw = Sww   + RN * NH;        // [2048]
    float*  WCw   = wsumw + RN;             // [256,256]
    float*  vw    = WCw   + (size_t)NH * NH;// [256]
    float4* rsw   = (float4*)(vw + NH);     // [2048]

    k_prep<<<65,               256, 0, stream>>>(We2, be2, Wn1, WCw, vw);
    k_pq  <<<(int)(RN / RP),   256, 0, stream>>>(slots, We1, be1, Wn1, Ptw, Qw, XWw, rsw);
    k_msg <<<(int)(RN / IBLK), 256, 0, stream>>>(adj, Ptw, Qw, rsw, ge, bge, Sww, wsumw);
    k_node<<<(int)(RN / 4),    512, 0, stream>>>(slots, Sww, wsumw, XWw, WCw, vw,
                                                 bn1, gn, bgn, Wn2, bn2, out);
}

// Round 6
// 62.721 us; speedup vs baseline: 1.3387x; 1.1453x over previous
//
#include <hip/hip_runtime.h>

#define NB 32
#define NN 64
#define ND 128
#define NH 256
#define LN_EPS 1e-5f
#define RP 4

// ---- branchless erf-based GELU, A&S 7.1.25 (|erf err| <= 5e-4), no exp ----
// returns 2*gelu(x) = x*(1+erf(x/sqrt2)) ; caller folds the 0.5
__device__ __forceinline__ float gelu2(float x) {
    const float au = fabsf(x);
    const float z  = au * 0.70710678118654752440f;
    float p = fmaf(0.078108f, z, 0.000972f);
    p = fmaf(p, z, 0.230389f);
    p = fmaf(p, z, 0.278393f);
    p = fmaf(p, z, 1.0f);
    const float p2 = p * p;
    const float r  = __builtin_amdgcn_rcpf(p2 * p2);   // (..)^-4 ; inf -> 0 (erf->1)
    return (x + au) - au * r;
}
__device__ __forceinline__ float gelu_h(float x) { return 0.5f * gelu2(x); }

// ---------------- K1 merged: [blocks 0..511] Pt/Qm/XW + rowstats ; [512..576] WC/v ----------------
__global__ __launch_bounds__(256) void k_pre(const float* __restrict__ slots,
                                             const float* __restrict__ We1,
                                             const float* __restrict__ be1,
                                             const float* __restrict__ Wn1,
                                             const float* __restrict__ We2,
                                             const float* __restrict__ be2,
                                             float* __restrict__ Pt,
                                             float* __restrict__ Qm,
                                             float* __restrict__ XW,
                                             float4* __restrict__ rowstats,
                                             float* __restrict__ WC,
                                             float* __restrict__ v) {
    __shared__ float xs[RP][ND];
    __shared__ float red[4][RP][4];
    const int t = threadIdx.x;

    if (blockIdx.x >= 512) {           // ---- prep role ----
        const int bid2 = blockIdx.x - 512;
        if (bid2 == 64) {              // v = be2 @ Wn1_bot
            __shared__ float bs[ND];
            if (t < ND) bs[t] = be2[t];
            __syncthreads();
            float acc = 0.f;
            #pragma unroll 4
            for (int d = 0; d < ND; ++d) acc = fmaf(bs[d], Wn1[(ND + d) * NH + t], acc);
            v[t] = acc;
            return;
        }
        const int k0 = bid2 * 4;       // WC rows k0..k0+3
        __shared__ float ws[4][ND];
        #pragma unroll
        for (int i = 0; i < 2; ++i) {
            const int idx = t + i * 256;
            ws[idx >> 7][idx & 127] = We2[(k0 + (idx >> 7)) * ND + (idx & 127)];
        }
        __syncthreads();
        float acc[4] = {0.f, 0.f, 0.f, 0.f};
        #pragma unroll 4
        for (int d = 0; d < ND; ++d) {
            const float wn = Wn1[(ND + d) * NH + t];
            #pragma unroll
            for (int r = 0; r < 4; ++r) acc[r] = fmaf(ws[r][d], wn, acc[r]);
        }
        #pragma unroll
        for (int r = 0; r < 4; ++r) WC[(k0 + r) * NH + t] = acc[r];
        return;
    }

    // ---- pq role ----
    const int r0 = blockIdx.x * RP;
    const int lane = t & 63, wave = t >> 6;
    #pragma unroll
    for (int i = 0; i < 2; ++i) {
        const int idx = t + i * 256;
        xs[idx >> 7][idx & 127] = slots[(size_t)(r0 + (idx >> 7)) * ND + (idx & 127)];
    }
    __syncthreads();
    float pt[RP], qq[RP], xw[RP];
    const float bb = be1[t];
    #pragma unroll
    for (int r = 0; r < RP; ++r) { pt[r] = bb; qq[r] = 0.f; xw[r] = 0.f; }
    #pragma unroll 4
    for (int d = 0; d < ND; ++d) {
        const float wt  = We1[d * NH + t];
        const float wbt = We1[(ND + d) * NH + t];
        const float wn  = Wn1[d * NH + t];
        #pragma unroll
        for (int r = 0; r < RP; ++r) {
            const float x = xs[r][d];
            pt[r] = fmaf(x, wt,  pt[r]);
            qq[r] = fmaf(x, wbt, qq[r]);
            xw[r] = fmaf(x, wn,  xw[r]);
        }
    }
    #pragma unroll
    for (int r = 0; r < RP; ++r) {
        const size_t row = (size_t)(r0 + r);
        Pt[row * NH + t] = pt[r];
        Qm[row * NH + t] = qq[r];
        XW[row * NH + t] = xw[r];
    }
    float s1[RP], s2[RP], s3[RP], s4[RP];
    #pragma unroll
    for (int r = 0; r < RP; ++r) {
        s1[r] = pt[r]; s2[r] = pt[r] * pt[r];
        s3[r] = qq[r]; s4[r] = qq[r] * qq[r];
    }
    #pragma unroll
    for (int off = 32; off; off >>= 1) {
        #pragma unroll
        for (int r = 0; r < RP; ++r) {
            s1[r] += __shfl_xor(s1[r], off);
            s2[r] += __shfl_xor(s2[r], off);
            s3[r] += __shfl_xor(s3[r], off);
            s4[r] += __shfl_xor(s4[r], off);
        }
    }
    if (lane == 0) {
        #pragma unroll
        for (int r = 0; r < RP; ++r) {
            red[wave][r][0] = s1[r]; red[wave][r][1] = s2[r];
            red[wave][r][2] = s3[r]; red[wave][r][3] = s4[r];
        }
    }
    __syncthreads();
    if (t < RP) {
        float4 st;
        st.x = (red[0][t][0] + red[1][t][0]) + (red[2][t][0] + red[3][t][0]);
        st.y = (red[0][t][1] + red[1][t][1]) + (red[2][t][1] + red[3][t][1]);
        st.z = (red[0][t][2] + red[1][t][2]) + (red[2][t][2] + red[3][t][2]);
        st.w = (red[0][t][3] + red[1][t][3]) + (red[2][t][3] + red[3][t][3]);
        rowstats[r0 + t] = st;
    }
}

// ---------------- K2: one row per block (2048 blocks, 8 blocks/CU) ----------------
__global__ __launch_bounds__(256) void k_msg(
    const float* __restrict__ adj,
    const float* __restrict__ Pt,
    const float* __restrict__ Qm,
    const float4* __restrict__ rowstats,
    const float* __restrict__ ge,  const float* __restrict__ bge,
    float* __restrict__ Sw, float* __restrict__ wsumw)
{
    __shared__ float  lds_pt[NH];
    __shared__ float4 lds_wmr[NN];    // {0.5w, rr, -mu*rr, w}
    __shared__ float  lds_s[4][NH];

    const int row = blockIdx.x;       // b*NN + i
    const int b   = row >> 6;
    const int i   = row & 63;
    const int t   = threadIdx.x;
    const int lane = t & 63;
    const int wave = t >> 6;

    lds_pt[t] = Pt[(size_t)row * NH + t];
    __syncthreads();

    // C-dot: j = t>>2, part = t&3 (64 channels each)
    const int jp = t >> 2, part = t & 3;
    {
        float cd = 0.f;
        const float4* qrow = (const float4*)(Qm + ((size_t)b * NN + jp) * NH) + part * 16;
        const float4* pr   = (const float4*)lds_pt + part * 16;
        #pragma unroll 4
        for (int k = 0; k < 16; ++k) {
            const float4 q = qrow[k];
            const float4 p = pr[k];
            cd = fmaf(p.x, q.x, fmaf(p.y, q.y, fmaf(p.z, q.z, fmaf(p.w, q.w, cd))));
        }
        cd += __shfl_xor(cd, 1); cd += __shfl_xor(cd, 2);
        if (part == 0) {
            const float inv = 1.0f / NH;
            const float4 stj = rowstats[(size_t)b * NN + jp];
            const float4 sti = rowstats[row];
            float a = adj[(size_t)row * NN + jp];
            if (jp == i) a = 0.f;                     // diagonal mask
            const float mu = (sti.x + stj.z) * inv;
            const float e2 = fmaf(2.f, cd, sti.y + stj.w) * inv;
            const float rr = __builtin_amdgcn_rsqf(fmaf(-mu, mu, e2) + LN_EPS);
            lds_wmr[jp] = make_float4(0.5f * a, rr, -mu * rr, a);
        }
    }
    __syncthreads();

    if (wave == 0) {                  // wsum, off critical path
        float wv = lds_wmr[lane].w;
        #pragma unroll
        for (int off = 32; off; off >>= 1) wv += __shfl_xor(wv, off);
        if (lane == 0) wsumw[row] = wv;
    }

    // main loop: no cross-lane ops, no branches; 10 VALU + 1 trans gelu
    const float4 P  = ((const float4*)lds_pt)[lane];
    const float4 G  = ((const float4*)ge)[lane];
    const float4 Bg = ((const float4*)bge)[lane];
    const float4* Qb = (const float4*)(Qm + (size_t)b * NN * NH);
    float4 A = make_float4(0.f, 0.f, 0.f, 0.f);
    #pragma unroll 4
    for (int jj = wave; jj < NN; jj += 4) {
        const float4 q = Qb[jj * (NH / 4) + lane];
        const float4 m = lds_wmr[jj];
        float h, u0, u;
        h = P.x + q.x; u0 = fmaf(h, m.y, m.z); u = fmaf(u0, G.x, Bg.x); A.x = fmaf(m.x, gelu2(u), A.x);
        h = P.y + q.y; u0 = fmaf(h, m.y, m.z); u = fmaf(u0, G.y, Bg.y); A.y = fmaf(m.x, gelu2(u), A.y);
        h = P.z + q.z; u0 = fmaf(h, m.y, m.z); u = fmaf(u0, G.z, Bg.z); A.z = fmaf(m.x, gelu2(u), A.z);
        h = P.w + q.w; u0 = fmaf(h, m.y, m.z); u = fmaf(u0, G.w, Bg.w); A.w = fmaf(m.x, gelu2(u), A.w);
    }
    ((float4*)lds_s[wave])[lane] = A;
    __syncthreads();
    Sw[(size_t)row * NH + t] =
        (lds_s[0][t] + lds_s[1][t]) + (lds_s[2][t] + lds_s[3][t]);
}

// ---------------- K3: h1 = XW + S@WC + wsum*v + bn1 ; LN ; GELU ; out = x + g@Wn2 + bn2 ----------------
__global__ __launch_bounds__(512) void k_node(
    const float* __restrict__ slots,
    const float* __restrict__ Sw, const float* __restrict__ wsumw,
    const float* __restrict__ XW,
    const float* __restrict__ WC, const float* __restrict__ v,
    const float* __restrict__ bn1,
    const float* __restrict__ gn,  const float* __restrict__ bgn,
    const float* __restrict__ Wn2, const float* __restrict__ bn2,
    float* __restrict__ out)
{
    __shared__ float lds_S[4][NH];
    __shared__ float lds_part[4][NH];
    __shared__ float lds_g[4][NH];
    __shared__ float lds_red[4][4][2];
    __shared__ float lds_mr[4][2];

    const int r0   = blockIdx.x * 4;
    const int t    = threadIdx.x;
    const int c    = t & 255;
    const int kh   = t >> 8;
    const int lane = t & 63;
    const int wave = t >> 6;

    lds_S[kh * 2 + 0][c] = Sw[(size_t)(r0 + kh * 2 + 0) * NH + c];
    lds_S[kh * 2 + 1][c] = Sw[(size_t)(r0 + kh * 2 + 1) * NH + c];
    __syncthreads();

    // partial S@WC over this half's k range
    float acc[4] = {0.f, 0.f, 0.f, 0.f};
    {
        const float* wc = WC + (size_t)kh * 128 * NH + c;
        #pragma unroll 8
        for (int k = 0; k < 128; ++k) {
            const float w = wc[k * NH];
            const int kk = kh * 128 + k;
            acc[0] = fmaf(lds_S[0][kk], w, acc[0]);
            acc[1] = fmaf(lds_S[1][kk], w, acc[1]);
            acc[2] = fmaf(lds_S[2][kk], w, acc[2]);
            acc[3] = fmaf(lds_S[3][kk], w, acc[3]);
        }
    }
    if (kh == 1) {
        #pragma unroll
        for (int r = 0; r < 4; ++r) lds_part[r][c] = acc[r];
    }
    __syncthreads();

    float h[4];
    if (kh == 0) {
        const float b1 = bn1[c], vc = v[c];
        #pragma unroll
        for (int r = 0; r < 4; ++r)
            h[r] = acc[r] + lds_part[r][c] + fmaf(wsumw[r0 + r], vc, b1)
                 + XW[(size_t)(r0 + r) * NH + c];
        float s1[4], s2[4];
        #pragma unroll
        for (int r = 0; r < 4; ++r) { s1[r] = h[r]; s2[r] = h[r] * h[r]; }
        #pragma unroll
        for (int off = 32; off; off >>= 1) {
            #pragma unroll
            for (int r = 0; r < 4; ++r) {
                s1[r] += __shfl_xor(s1[r], off);
                s2[r] += __shfl_xor(s2[r], off);
            }
        }
        if (lane == 0) {
            #pragma unroll
            for (int r = 0; r < 4; ++r) { lds_red[wave][r][0] = s1[r]; lds_red[wave][r][1] = s2[r]; }
        }
    }
    __syncthreads();
    if (t < 4) {
        const float S1 = (lds_red[0][t][0] + lds_red[1][t][0]) + (lds_red[2][t][0] + lds_red[3][t][0]);
        const float S2 = (lds_red[0][t][1] + lds_red[1][t][1]) + (lds_red[2][t][1] + lds_red[3][t][1]);
        const float mu  = S1 * (1.0f / NH);
        const float var = fmaf(-mu, mu, S2 * (1.0f / NH));
        lds_mr[t][0] = mu;
        lds_mr[t][1] = __builtin_amdgcn_rsqf(var + LN_EPS);
    }
    __syncthreads();
    if (kh == 0) {
        const float g = gn[c], bg = bgn[c];
        #pragma unroll
        for (int r = 0; r < 4; ++r) {
            const float rr = lds_mr[r][1];
            const float u0 = fmaf(h[r], rr, -lds_mr[r][0] * rr);
            lds_g[r][c] = gelu_h(fmaf(u0, g, bg));
        }
    }
    __syncthreads();

    // delta = g @ Wn2 + bn2 ; out = x + delta
    {
        const int rg = t >> 7, c2 = t & 127;
        float da = 0.f, db = 0.f;
        const float* w2 = Wn2 + c2;
        const float* gr = lds_g[rg];
        #pragma unroll 8
        for (int k = 0; k < NH; k += 2) {
            da = fmaf(gr[k],     w2[k * ND],       da);
            db = fmaf(gr[k + 1], w2[(k + 1) * ND], db);
        }
        const size_t o = (size_t)(r0 + rg) * ND + c2;
        out[o] = slots[o] + bn2[c2] + da + db;
    }
}

extern "C" void kernel_launch(void* const* d_in, const int* in_sizes, int n_in,
                              void* d_out, int out_size, void* d_ws, size_t ws_size,
                              hipStream_t stream) {
    const float* slots = (const float*)d_in[0];
    const float* adj   = (const float*)d_in[1];
    const float* We1   = (const float*)d_in[2];
    const float* be1   = (const float*)d_in[3];
    const float* ge    = (const float*)d_in[4];
    const float* bge   = (const float*)d_in[5];
    const float* We2   = (const float*)d_in[6];
    const float* be2   = (const float*)d_in[7];
    const float* Wn1   = (const float*)d_in[8];
    const float* bn1   = (const float*)d_in[9];
    const float* gn    = (const float*)d_in[10];
    const float* bgn   = (const float*)d_in[11];
    const float* Wn2   = (const float*)d_in[12];
    const float* bn2   = (const float*)d_in[13];
    float* out = (float*)d_out;

    const size_t RN = (size_t)NB * NN;      // 2048
    float*  Ptw   = (float*)d_ws;           // [2048,256]
    float*  Qw    = Ptw   + RN * NH;        // [2048,256]
    float*  XWw   = Qw    + RN * NH;        // [2048,256]
    float*  Sww   = XWw   + RN * NH;        // [2048,256]
    float*  wsumw = Sww   + RN * NH;        // [2048]
    float*  WCw   = wsumw + RN;             // [256,256]
    float*  vw    = WCw   + (size_t)NH * NH;// [256]
    float4* rsw   = (float4*)(vw + NH);     // [2048]

    k_pre <<<577,          256, 0, stream>>>(slots, We1, be1, Wn1, We2, be2,
                                             Ptw, Qw, XWw, rsw, WCw, vw);
    k_msg <<<(int)RN,      256, 0, stream>>>(adj, Ptw, Qw, rsw, ge, bge, Sww, wsumw);
    k_node<<<(int)(RN / 4), 512, 0, stream>>>(slots, Sww, wsumw, XWw, WCw, vw,
                                              bn1, gn, bgn, Wn2, bn2, out);
}